// Round 9
// baseline (39.474 us; speedup 1.0000x reference)
//
#include <hip/hip_runtime.h>
#include <math.h>

#define NB 32
#define NN 1024
#define NF 512

// ---------------- transpose W[NN][NF] -> Wt[NF][NN] ----------------
__global__ __launch_bounds__(256) void transpose_w_k(const float* __restrict__ W,
                                                     float* __restrict__ Wt) {
    __shared__ float tile[32][33];
    int n0 = blockIdx.x * 32;
    int f0 = blockIdx.y * 32;
    int tx = threadIdx.x & 31;
    int ty = threadIdx.x >> 5;  // 0..7
#pragma unroll
    for (int r = 0; r < 32; r += 8) {
        tile[ty + r][tx] = W[(n0 + ty + r) * NF + (f0 + tx)];
    }
    __syncthreads();
#pragma unroll
    for (int r = 0; r < 32; r += 8) {
        Wt[(f0 + ty + r) * NN + (n0 + tx)] = tile[tx][ty + r];
    }
}

// ---------------- DPP wave64 reductions (VALU-only, no DS pipe) ----------------
#define DPP_XOR1        0xB1   // quad_perm [1,0,3,2]
#define DPP_XOR2        0x4E   // quad_perm [2,3,0,1]
#define DPP_HALF_MIRROR 0x141
#define DPP_MIRROR      0x140
#define DPP_BCAST15     0x142
#define DPP_BCAST31     0x143

template <int CTRL>
__device__ __forceinline__ float dpp_mov(float v) {
    return __int_as_float(__builtin_amdgcn_update_dpp(
        0, __float_as_int(v), CTRL, 0xf, 0xf, true));
}

// wave-wide sum, wave-uniform result
__device__ __forceinline__ float wave_sum_u(float v) {
    v += dpp_mov<DPP_XOR1>(v);
    v += dpp_mov<DPP_XOR2>(v);
    v += dpp_mov<DPP_HALF_MIRROR>(v);
    v += dpp_mov<DPP_MIRROR>(v);
    v += dpp_mov<DPP_BCAST15>(v);
    v += dpp_mov<DPP_BCAST31>(v);
    return __int_as_float(__builtin_amdgcn_readlane(__float_as_int(v), 63));
}
// wave-wide max of NON-NEGATIVE values (bound_ctrl zeros are max-identity)
__device__ __forceinline__ float wave_max_u(float v) {
    v = fmaxf(v, dpp_mov<DPP_XOR1>(v));
    v = fmaxf(v, dpp_mov<DPP_XOR2>(v));
    v = fmaxf(v, dpp_mov<DPP_HALF_MIRROR>(v));
    v = fmaxf(v, dpp_mov<DPP_MIRROR>(v));
    v = fmaxf(v, dpp_mov<DPP_BCAST15>(v));
    v = fmaxf(v, dpp_mov<DPP_BCAST31>(v));
    return __int_as_float(__builtin_amdgcn_readlane(__float_as_int(v), 63));
}

__device__ __forceinline__ float fast_sqrt(float v) { return __builtin_amdgcn_sqrtf(v); }
__device__ __forceinline__ float fast_rcp(float v)  { return __builtin_amdgcn_rcpf(v); }

// ---------------- hot-path solver ----------------
// Solve F(t) = sum_j relu(m_j - t) = 1 on t in [0, M] for both sides.
// 5 secant sweeps (3 in sqrt(E) space — exact for the quadratic bulk model;
// 2 in E space — exact in the final linear segment), then 2 count-based plain
// Newton polish sweeps (t += (E-1)/c; exact within a linear segment, proven
// convergent in R1-R7's hybrid). t<=M clamp guarantees c>=1 (no rcp(0)).
// ALL internal variables carry trailing underscores: R8 FAILED because the
// macro declared `float tp` shadowing the caller's `tp` output variable, so
// `TP_OUT = tp` was a self-assignment and the caller got uninitialized values
// (all-zero output, absmax == max|ref| == 2.136e-2 — round-0 stub signature).
#define FAST_SOLVE(MP, MM, SP, SM, MPX, MMX, TP_OUT, TM_OUT)                          \
    {                                                                                 \
        float tpp_ = 0.0f, Epp_ = SP;                                                 \
        float tmp2_ = 0.0f, Emp_ = SM;                                                \
        float tp_ = fminf(2.0f * (SP - fast_sqrt(SP)) * (1.0f/1024.0f), MPX);         \
        float tm_ = fminf(2.0f * (SM - fast_sqrt(SM)) * (1.0f/1024.0f), MMX);         \
        _Pragma("unroll")                                                             \
        for (int s_ = 0; s_ < 5; ++s_) {                                              \
            float ep_ = 0.f, em_ = 0.f;                                               \
            _Pragma("unroll")                                                         \
            for (int j_ = 0; j_ < 16; ++j_) {                                         \
                ep_ += fmaxf(MP[j_] - tp_, 0.0f);                                     \
                em_ += fmaxf(MM[j_] - tm_, 0.0f);                                     \
            }                                                                         \
            ep_ = wave_sum_u(ep_);                                                    \
            em_ = wave_sum_u(em_);                                                    \
            float rp_, rm_, rpp_, rmp_;                                               \
            if (s_ < 3) { rp_ = fast_sqrt(ep_);  rm_ = fast_sqrt(em_);                \
                          rpp_ = fast_sqrt(Epp_); rmp_ = fast_sqrt(Emp_); }           \
            else        { rp_ = ep_; rm_ = em_; rpp_ = Epp_; rmp_ = Emp_; }           \
            float denp_ = rp_ - rpp_, denm_ = rm_ - rmp_;                             \
            float stp_ = (denp_ != 0.0f)                                              \
                       ? (tp_ - tpp_) * (1.0f - rp_) * fast_rcp(denp_) : 0.0f;        \
            float stm_ = (denm_ != 0.0f)                                              \
                       ? (tm_ - tmp2_) * (1.0f - rm_) * fast_rcp(denm_) : 0.0f;       \
            tpp_ = tp_; Epp_ = ep_; tmp2_ = tm_; Emp_ = em_;                          \
            tp_ = fminf(fmaxf(tp_ + stp_, 0.0f), MPX);                                \
            tm_ = fminf(fmaxf(tm_ + stm_, 0.0f), MMX);                                \
        }                                                                             \
        _Pragma("unroll")                                                             \
        for (int q_ = 0; q_ < 2; ++q_) {                                              \
            float ep_ = 0.f, cp_ = 0.f, em_ = 0.f, cm_ = 0.f;                         \
            _Pragma("unroll")                                                         \
            for (int j_ = 0; j_ < 16; ++j_) {                                         \
                float dp_ = MP[j_] - tp_;                                             \
                float dm_ = MM[j_] - tm_;                                             \
                bool ap_ = (dp_ >= 0.0f);                                             \
                bool am_ = (dm_ >= 0.0f);                                             \
                ep_ += ap_ ? dp_ : 0.0f;  cp_ += ap_ ? 1.0f : 0.0f;                   \
                em_ += am_ ? dm_ : 0.0f;  cm_ += am_ ? 1.0f : 0.0f;                   \
            }                                                                         \
            ep_ = wave_sum_u(ep_); cp_ = wave_sum_u(cp_);                             \
            em_ = wave_sum_u(em_); cm_ = wave_sum_u(cm_);                             \
            tp_ = fminf(fmaxf(tp_ + (ep_ - 1.0f) * fast_rcp(cp_), 0.0f), MPX);        \
            tm_ = fminf(fmaxf(tm_ + (em_ - 1.0f) * fast_rcp(cm_), 0.0f), MMX);        \
        }                                                                             \
        TP_OUT = tp_; TM_OUT = tm_;                                                   \
    }

// Cold-path exact solver (root may be > 0), macro-expanded: NO pointer to the
// register arrays is ever taken (runtime-indexed pointers spill to scratch).
#define COLD_SOLVE(MARR, SV, MV, NEGV, RESV)                                     \
    if (NEGV) {                                                                  \
        float t_ = fminf(fmaxf(2.0f * (SV - fast_sqrt(SV)) * (1.0f/1024.0f), 0.0f), MV); \
        _Pragma("unroll 1")                                                      \
        for (int s_ = 0; s_ < 20; ++s_) {                                        \
            float ss_ = 0.f; int c_ = 0;                                         \
            _Pragma("unroll")                                                    \
            for (int j_ = 0; j_ < 16; ++j_) {                                    \
                bool pr_ = (MARR[j_] >= t_);                                     \
                c_ += (int)__popcll(__ballot(pr_));                              \
                ss_ += pr_ ? MARR[j_] : 0.0f;                                    \
            }                                                                    \
            ss_ = wave_sum_u(ss_);                                               \
            float fc_ = (float)c_;                                               \
            float E_ = ss_ - t_ * fc_;                                           \
            float d_ = (E_ >= 1.0f) ? 2.0f * (E_ - fast_sqrt(E_)) : (E_ - 1.0f); \
            t_ = fminf(fmaxf(t_ + d_ * fast_rcp(fc_), 0.0f), MV);                \
        }                                                                        \
        RESV = -t_;                                                              \
    } else {                                                                     \
        float u_ = (1.0f - SV) * (1.0f/1024.0f);                                 \
        _Pragma("unroll 1")                                                      \
        for (int s_ = 0; s_ < 12; ++s_) {                                        \
            float s2_ = 0.f; int c2_ = 0;                                        \
            _Pragma("unroll")                                                    \
            for (int j_ = 0; j_ < 16; ++j_) {                                    \
                bool pr_ = (MARR[j_] <= u_);                                     \
                c2_ += (int)__popcll(__ballot(pr_));                             \
                s2_ += pr_ ? MARR[j_] : 0.0f;                                    \
            }                                                                    \
            s2_ = wave_sum_u(s2_);                                               \
            u_ = (1.0f - SV + s2_) * fast_rcp(1024.0f + (float)c2_);             \
        }                                                                        \
        RESV = u_;                                                               \
    }

// setup helper: from x,w float4 -> m arrays + running sums/maxes
#define SETUP4(XV, WV, MP, MM, BASE, SPV, SMV, XPV, XMV)                         \
    {                                                                            \
        float ap_, am_;                                                          \
        ap_ = fabsf(XV.x + 0.5f * WV.x); am_ = fabsf(XV.x - 0.5f * WV.x);        \
        MP[BASE+0] = ap_; MM[BASE+0] = am_; SPV += ap_; SMV += am_;              \
        XPV = fmaxf(XPV, ap_); XMV = fmaxf(XMV, am_);                            \
        ap_ = fabsf(XV.y + 0.5f * WV.y); am_ = fabsf(XV.y - 0.5f * WV.y);        \
        MP[BASE+1] = ap_; MM[BASE+1] = am_; SPV += ap_; SMV += am_;              \
        XPV = fmaxf(XPV, ap_); XMV = fmaxf(XMV, am_);                            \
        ap_ = fabsf(XV.z + 0.5f * WV.z); am_ = fabsf(XV.z - 0.5f * WV.z);        \
        MP[BASE+2] = ap_; MM[BASE+2] = am_; SPV += ap_; SMV += am_;              \
        XPV = fmaxf(XPV, ap_); XMV = fmaxf(XMV, am_);                            \
        ap_ = fabsf(XV.w + 0.5f * WV.w); am_ = fabsf(XV.w - 0.5f * WV.w);        \
        MP[BASE+3] = ap_; MM[BASE+3] = am_; SPV += ap_; SMV += am_;              \
        XPV = fmaxf(XPV, ap_); XMV = fmaxf(XMV, am_);                            \
    }

// One wave per TWO outputs (b, f) and (b, f+256): shared x row, all loads
// issued up-front (one latency exposure per 2 outputs), 8192 waves total.
// Output = relu(u_p - u_m) = relu(t_m - t_p) in t-space.
__global__ __launch_bounds__(256) void spike_main_k(const float* __restrict__ x,
                                                    const float* __restrict__ Wt,
                                                    float* __restrict__ out) {
    int bid  = blockIdx.x;          // 0..2047
    int b    = bid >> 6;            // 0..31
    int fg   = bid & 63;            // 0..63
    int wave = threadIdx.x >> 6;    // 0..3
    int lane = threadIdx.x & 63;
    int f1   = fg * 4 + wave;       // 0..255
    int f2   = f1 + 256;            // 256..511

    const float4* x4  = reinterpret_cast<const float4*>(x + (size_t)b * NN);
    const float4* wa4 = reinterpret_cast<const float4*>(Wt + (size_t)f1 * NN);
    const float4* wb4 = reinterpret_cast<const float4*>(Wt + (size_t)f2 * NN);

    // issue ALL loads up front (12 x dwordx4): one memory-latency exposure
    float4 xr0 = x4[lane +   0], xr1 = x4[lane +  64],
           xr2 = x4[lane + 128], xr3 = x4[lane + 192];
    float4 wa0 = wa4[lane +   0], wa1 = wa4[lane +  64],
           wa2 = wa4[lane + 128], wa3 = wa4[lane + 192];
    float4 wb0 = wb4[lane +   0], wb1 = wb4[lane +  64],
           wb2 = wb4[lane + 128], wb3 = wb4[lane + 192];

    float mp1[16], mm1[16], mp2[16], mm2[16];
    float sp1 = 0.f, sm1 = 0.f, xp1 = 0.f, xm1 = 0.f;
    float sp2 = 0.f, sm2 = 0.f, xp2 = 0.f, xm2 = 0.f;

    SETUP4(xr0, wa0, mp1, mm1,  0, sp1, sm1, xp1, xm1);
    SETUP4(xr1, wa1, mp1, mm1,  4, sp1, sm1, xp1, xm1);
    SETUP4(xr2, wa2, mp1, mm1,  8, sp1, sm1, xp1, xm1);
    SETUP4(xr3, wa3, mp1, mm1, 12, sp1, sm1, xp1, xm1);
    SETUP4(xr0, wb0, mp2, mm2,  0, sp2, sm2, xp2, xm2);
    SETUP4(xr1, wb1, mp2, mm2,  4, sp2, sm2, xp2, xm2);
    SETUP4(xr2, wb2, mp2, mm2,  8, sp2, sm2, xp2, xm2);
    SETUP4(xr3, wb3, mp2, mm2, 12, sp2, sm2, xp2, xm2);

    // keep m arrays opaque: prevents rematerialization (reload+fma+abs) in sweeps
#pragma unroll
    for (int j = 0; j < 16; ++j) {
        asm volatile("" : "+v"(mp1[j]), "+v"(mm1[j]), "+v"(mp2[j]), "+v"(mm2[j]));
    }

    float Sp1 = wave_sum_u(sp1), Sm1 = wave_sum_u(sm1);
    float Mp1 = wave_max_u(xp1), Mm1 = wave_max_u(xm1);
    float Sp2 = wave_sum_u(sp2), Sm2 = wave_sum_u(sm2);
    float Mp2 = wave_max_u(xp2), Mm2 = wave_max_u(xm2);

    float o1, o2;

    if (Sp1 >= 1.0f && Sm1 >= 1.0f) {
        float tp1, tm1;
        FAST_SOLVE(mp1, mm1, Sp1, Sm1, Mp1, Mm1, tp1, tm1);
        o1 = fmaxf(tm1 - tp1, 0.0f);
    } else {
        float up1, um1;
        COLD_SOLVE(mp1, Sp1, Mp1, (Sp1 >= 1.0f), up1);
        COLD_SOLVE(mm1, Sm1, Mm1, (Sm1 >= 1.0f), um1);
        o1 = fmaxf(up1 - um1, 0.0f);
    }

    if (Sp2 >= 1.0f && Sm2 >= 1.0f) {
        float tp2, tm2;
        FAST_SOLVE(mp2, mm2, Sp2, Sm2, Mp2, Mm2, tp2, tm2);
        o2 = fmaxf(tm2 - tp2, 0.0f);
    } else {
        float up2, um2;
        COLD_SOLVE(mp2, Sp2, Mp2, (Sp2 >= 1.0f), up2);
        COLD_SOLVE(mm2, Sm2, Mm2, (Sm2 >= 1.0f), um2);
        o2 = fmaxf(up2 - um2, 0.0f);
    }

    if (lane == 0) {
        out[(size_t)b * NF + f1] = o1;
        out[(size_t)b * NF + f2] = o2;
    }
}

extern "C" void kernel_launch(void* const* d_in, const int* in_sizes, int n_in,
                              void* d_out, int out_size, void* d_ws, size_t ws_size,
                              hipStream_t stream) {
    const float* x = (const float*)d_in[0];   // 32 x 1024
    const float* W = (const float*)d_in[1];   // 1024 x 512
    float* out = (float*)d_out;               // 32 x 512
    float* Wt = (float*)d_ws;                 // needs 2MB; ws observed ~268MB

    dim3 g(NN / 32, NF / 32);  // 32 x 16
    transpose_w_k<<<g, 256, 0, stream>>>(W, Wt);
    spike_main_k<<<NB * (NF / 8), 256, 0, stream>>>(x, Wt, out);  // 2048 blocks
}

// Round 10
// 28.818 us; speedup vs baseline: 1.3698x; 1.3698x over previous
//
#include <hip/hip_runtime.h>
#include <math.h>

#define NB 32
#define NN 1024
#define NF 512

// ---------------- transpose W[NN][NF] -> Wt[NF][NN] ----------------
__global__ __launch_bounds__(256) void transpose_w_k(const float* __restrict__ W,
                                                     float* __restrict__ Wt) {
    __shared__ float tile[32][33];
    int n0 = blockIdx.x * 32;
    int f0 = blockIdx.y * 32;
    int tx = threadIdx.x & 31;
    int ty = threadIdx.x >> 5;  // 0..7
#pragma unroll
    for (int r = 0; r < 32; r += 8) {
        tile[ty + r][tx] = W[(n0 + ty + r) * NF + (f0 + tx)];
    }
    __syncthreads();
#pragma unroll
    for (int r = 0; r < 32; r += 8) {
        Wt[(f0 + ty + r) * NN + (n0 + tx)] = tile[tx][ty + r];
    }
}

// ---------------- DPP wave64 reductions (VALU-only, no DS pipe) ----------------
#define DPP_XOR1        0xB1   // quad_perm [1,0,3,2]
#define DPP_XOR2        0x4E   // quad_perm [2,3,0,1]
#define DPP_HALF_MIRROR 0x141
#define DPP_MIRROR      0x140
#define DPP_BCAST15     0x142
#define DPP_BCAST31     0x143

template <int CTRL>
__device__ __forceinline__ float dpp_mov(float v) {
    return __int_as_float(__builtin_amdgcn_update_dpp(
        0, __float_as_int(v), CTRL, 0xf, 0xf, true));
}

// wave-wide sum, wave-uniform result
__device__ __forceinline__ float wave_sum_u(float v) {
    v += dpp_mov<DPP_XOR1>(v);
    v += dpp_mov<DPP_XOR2>(v);
    v += dpp_mov<DPP_HALF_MIRROR>(v);
    v += dpp_mov<DPP_MIRROR>(v);
    v += dpp_mov<DPP_BCAST15>(v);
    v += dpp_mov<DPP_BCAST31>(v);
    return __int_as_float(__builtin_amdgcn_readlane(__float_as_int(v), 63));
}
// wave-wide max of NON-NEGATIVE values (bound_ctrl zeros are max-identity)
__device__ __forceinline__ float wave_max_u(float v) {
    v = fmaxf(v, dpp_mov<DPP_XOR1>(v));
    v = fmaxf(v, dpp_mov<DPP_XOR2>(v));
    v = fmaxf(v, dpp_mov<DPP_HALF_MIRROR>(v));
    v = fmaxf(v, dpp_mov<DPP_MIRROR>(v));
    v = fmaxf(v, dpp_mov<DPP_BCAST15>(v));
    v = fmaxf(v, dpp_mov<DPP_BCAST31>(v));
    return __int_as_float(__builtin_amdgcn_readlane(__float_as_int(v), 63));
}

__device__ __forceinline__ float fast_sqrt(float v) { return __builtin_amdgcn_sqrtf(v); }
__device__ __forceinline__ float fast_rcp(float v)  { return __builtin_amdgcn_rcpf(v); }

// One wave per (output, side): wave solves F(t) = sum_j relu(m_j - t) = 1 with
// m = |x + sgn*0.5*W| held 16/lane. EXACT R7 per-side numerics (proven floor
// 6.103516e-5 at 31.1us): quad-model warm start + 5 hybrid sweeps
// (E>=1: accelerated 2(E-sqrt(E))/c, else Newton (E-1)/c), clamped t in [0,M]
// so count>=1. All macro-internal names end in '_' (R8 shadowing lesson).
#define HYBRID5(MARR, SV, MV, RES_T)                                             \
    {                                                                            \
        float t_ = fminf(fmaxf(2.0f * (SV - fast_sqrt(SV)) * (1.0f/1024.0f),     \
                               0.0f), MV);                                       \
        _Pragma("unroll")                                                        \
        for (int s_ = 0; s_ < 5; ++s_) {                                         \
            float ss_ = 0.f; int c_ = 0;                                         \
            _Pragma("unroll")                                                    \
            for (int j_ = 0; j_ < 16; ++j_) {                                    \
                bool pr_ = (MARR[j_] >= t_);                                     \
                c_ += (int)__popcll(__ballot(pr_));                              \
                ss_ += pr_ ? MARR[j_] : 0.0f;                                    \
            }                                                                    \
            ss_ = wave_sum_u(ss_);                                               \
            float fc_ = (float)c_;                                               \
            float E_ = ss_ - t_ * fc_;                                           \
            float d_ = (E_ >= 1.0f) ? 2.0f * (E_ - fast_sqrt(E_)) : (E_ - 1.0f); \
            t_ = fminf(fmaxf(t_ + d_ * fast_rcp(fc_), 0.0f), MV);                \
        }                                                                        \
        RES_T = t_;                                                              \
    }

// Cold path (S < 1: root u > 0): g(u) = 1024u + S + sum_{m<=u}(u - m) = 1.
#define COLD_POS(MARR, SV, RES_U)                                                \
    {                                                                            \
        float u_ = (1.0f - SV) * (1.0f/1024.0f);                                 \
        _Pragma("unroll 1")                                                      \
        for (int s_ = 0; s_ < 12; ++s_) {                                        \
            float s2_ = 0.f; int c2_ = 0;                                        \
            _Pragma("unroll")                                                    \
            for (int j_ = 0; j_ < 16; ++j_) {                                    \
                bool pr_ = (MARR[j_] <= u_);                                     \
                c2_ += (int)__popcll(__ballot(pr_));                             \
                s2_ += pr_ ? MARR[j_] : 0.0f;                                    \
            }                                                                    \
            s2_ = wave_sum_u(s2_);                                               \
            u_ = (1.0f - SV + s2_) * fast_rcp(1024.0f + (float)c2_);             \
        }                                                                        \
        RES_U = u_;                                                              \
    }

// Block = 512 threads = 8 waves: waves 0-3 solve the PLUS side of outputs
// (b, f0..f0+3), waves 4-7 the MINUS side of the same outputs. Each wave's
// work is HALF of R7's (one side), doubling wave count to 32768 for better
// latency-bubble overlap; combine via 1 LDS word/wave + one barrier.
__global__ __launch_bounds__(512, 8) void spike_main_k(const float* __restrict__ x,
                                                       const float* __restrict__ Wt,
                                                       float* __restrict__ out) {
    __shared__ float ures[8];

    int bid  = blockIdx.x;           // 0..4095
    int b    = bid >> 7;             // 0..31
    int fg   = bid & 127;            // 0..127
    int wave = threadIdx.x >> 6;     // 0..7
    int lane = threadIdx.x & 63;
    int side = wave >> 2;            // 0 = plus, 1 = minus
    int fi   = wave & 3;
    int f    = fg * 4 + fi;          // 0..511

    const float4* x4 = reinterpret_cast<const float4*>(x + (size_t)b * NN);
    const float4* w4 = reinterpret_cast<const float4*>(Wt + (size_t)f * NN);

    const float h = side ? -0.5f : 0.5f;

    float m[16];
    float s0 = 0.f, x0 = 0.f;
#pragma unroll
    for (int j = 0; j < 4; ++j) {
        float4 xv = x4[lane + 64 * j];
        float4 wv = w4[lane + 64 * j];
        float a;
        a = fabsf(fmaf(h, wv.x, xv.x)); m[4*j+0] = a; s0 += a; x0 = fmaxf(x0, a);
        a = fabsf(fmaf(h, wv.y, xv.y)); m[4*j+1] = a; s0 += a; x0 = fmaxf(x0, a);
        a = fabsf(fmaf(h, wv.z, xv.z)); m[4*j+2] = a; s0 += a; x0 = fmaxf(x0, a);
        a = fabsf(fmaf(h, wv.w, xv.w)); m[4*j+3] = a; s0 += a; x0 = fmaxf(x0, a);
    }

    // keep m opaque: prevents rematerialization (reload+fma+abs) inside sweeps
#pragma unroll
    for (int j = 0; j < 16; ++j) {
        asm volatile("" : "+v"(m[j]));
    }

    float S = wave_sum_u(s0);
    float M = wave_max_u(x0);

    float u;
    if (S >= 1.0f) {          // root <= 0 (always, for this data)
        float t;
        HYBRID5(m, S, M, t);
        u = -t;
    } else {                  // general case: root > 0
        COLD_POS(m, S, u);
    }

    if (lane == 0) ures[wave] = u;
    __syncthreads();

    if (wave < 4 && lane == 0) {
        // out = relu(u_plus - u_minus)
        out[(size_t)b * NF + f] = fmaxf(ures[wave] - ures[wave + 4], 0.0f);
    }
}

extern "C" void kernel_launch(void* const* d_in, const int* in_sizes, int n_in,
                              void* d_out, int out_size, void* d_ws, size_t ws_size,
                              hipStream_t stream) {
    const float* x = (const float*)d_in[0];   // 32 x 1024
    const float* W = (const float*)d_in[1];   // 1024 x 512
    float* out = (float*)d_out;               // 32 x 512
    float* Wt = (float*)d_ws;                 // needs 2MB scratch

    dim3 g(NN / 32, NF / 32);  // 32 x 16
    transpose_w_k<<<g, 256, 0, stream>>>(W, Wt);
    spike_main_k<<<4096, 512, 0, stream>>>(x, Wt, out);
}